// Round 18
// baseline (83.755 us; speedup 1.0000x reference)
//
#include <hip/hip_runtime.h>

#define L 1024
#define DM 1024
#define NH 16
#define DK 64

typedef __attribute__((ext_vector_type(8))) short bf16x8;
typedef __attribute__((ext_vector_type(4))) float f32x4;
typedef _Float16 h2 __attribute__((ext_vector_type(2)));
typedef _Float16 f16x8 __attribute__((ext_vector_type(8)));

#define MFMA(a, b, c) __builtin_amdgcn_mfma_f32_16x16x32_bf16(a, b, c, 0, 0, 0)
#define MFMA16(a, b, c) __builtin_amdgcn_mfma_f32_16x16x32_f16(a, b, c, 0, 0, 0)

__device__ inline unsigned short f2bf(float f) {
    unsigned int u = __builtin_bit_cast(unsigned int, f);
    u += 0x7FFFu + ((u >> 16) & 1u);
    return (unsigned short)(u >> 16);
}
__device__ inline unsigned short f2h(float f) {
    return __builtin_bit_cast(unsigned short, (_Float16)f);
}
__device__ inline float h2f(unsigned short u) {
    return (float)__builtin_bit_cast(_Float16, u);
}

__device__ inline h2 h2splat(float v) {
    h2 r; r[0] = (_Float16)v; r[1] = (_Float16)v; return r;
}
__device__ inline h2 h2max(h2 a, h2 b) {
#if defined(__has_builtin)
#if __has_builtin(__builtin_elementwise_max)
    return __builtin_elementwise_max(a, b);
#else
    h2 r; r[0] = a[0] > b[0] ? a[0] : b[0]; r[1] = a[1] > b[1] ? a[1] : b[1]; return r;
#endif
#else
    h2 r; r[0] = a[0] > b[0] ? a[0] : b[0]; r[1] = a[1] > b[1] ? a[1] : b[1]; return r;
#endif
}

// f32-accumulating fp16 pair dot
__device__ inline float dot2acc(h2 a, h2 b, float c) {
#if defined(__has_builtin)
#if __has_builtin(__builtin_amdgcn_fdot2)
    return __builtin_amdgcn_fdot2(a, b, c, false);
#else
    return c + (float)a[0] * (float)b[0] + (float)a[1] * (float)b[1];
#endif
#else
    return c + (float)a[0] * (float)b[0] + (float)a[1] * (float)b[1];
#endif
}

// ---------------------------------------------------------------------------
// Prep: fp32 -> bf16 conversion of GEMM inputs + mask -> fp16 bias fragments.
// ---------------------------------------------------------------------------
__global__ __launch_bounds__(256) void prep_kernel(
    const float* __restrict__ q, const float* __restrict__ k, const float* __restrict__ v,
    const float* __restrict__ wq, const float* __restrict__ wk,
    const float* __restrict__ wv, const float* __restrict__ wo,
    const int* __restrict__ mask,
    unsigned short* __restrict__ Xq, unsigned short* __restrict__ Xk,
    unsigned short* __restrict__ Xv, unsigned short* __restrict__ Wq,
    unsigned short* __restrict__ Wk, unsigned short* __restrict__ Wv,
    unsigned short* __restrict__ Wo, unsigned short* __restrict__ Mp)
{
    const int id = blockIdx.x * 256 + threadIdx.x;     // 0 .. 262143
    {   // mask packing: Mp[qtile][kblk][lane][4]
        int lane = id & 63;
        int kblk = (id >> 6) & 63;
        int qtile = id >> 12;
        int qabs = qtile * 16 + (lane & 15);
        int kcol = kblk * 16 + (lane >> 4) * 4;
        int4 m = *(const int4*)&mask[(size_t)qabs * L + kcol];
        unsigned short neg = f2h(-60000.0f);
        ushort4 o;
        o.x = (m.x == 0) ? neg : (unsigned short)0;
        o.y = (m.y == 0) ? neg : (unsigned short)0;
        o.z = (m.z == 0) ? neg : (unsigned short)0;
        o.w = (m.w == 0) ? neg : (unsigned short)0;
        *(ushort4*)&Mp[(size_t)id * 4] = o;
    }

    const size_t M2 = (size_t)1 << 21, M1 = (size_t)1 << 20;
    const size_t nchunks = (3 * M2 + 4 * M1) / 8;
    const size_t stride = (size_t)gridDim.x * blockDim.x;
    for (size_t c = (size_t)id; c < nchunks; c += stride) {
        size_t e = c * 8;
        const float* src;
        unsigned short* dst;
        size_t off;
        if (e < 3 * M2) {
            size_t r = e / M2;
            off = e - r * M2;
            src = r == 0 ? q : (r == 1 ? k : v);
            dst = r == 0 ? Xq : (r == 1 ? Xk : Xv);
        } else {
            size_t e2 = e - 3 * M2;
            size_t r = e2 / M1;
            off = e2 - r * M1;
            src = r == 0 ? wq : (r == 1 ? wk : (r == 2 ? wv : wo));
            dst = r == 0 ? Wq : (r == 1 ? Wk : (r == 2 ? Wv : Wo));
        }
        float4 a = *(const float4*)&src[off];
        float4 b = *(const float4*)&src[off + 4];
        ushort4 o0, o1;
        o0.x = f2bf(a.x); o0.y = f2bf(a.y); o0.z = f2bf(a.z); o0.w = f2bf(a.w);
        o1.x = f2bf(b.x); o1.y = f2bf(b.y); o1.z = f2bf(b.z); o1.w = f2bf(b.w);
        *(ushort4*)&dst[off] = o0;
        *(ushort4*)&dst[off + 4] = o1;
    }
}

// ---------------------------------------------------------------------------
// Projections: Y = X @ W^T from pre-converted bf16. T14 pipeline.
//  z=0/1: Q/K fp16 fragment-packed;  z=2: V fp16 fragment-packed.
// BM=128, BN=64, BK=64, 256 thr / 4 waves. grid 768 flat, XCD remap.
// ---------------------------------------------------------------------------
__global__ __launch_bounds__(256) void proj_kernel(
    const unsigned short* __restrict__ Xq, const unsigned short* __restrict__ Xk,
    const unsigned short* __restrict__ Xv, const unsigned short* __restrict__ Wq,
    const unsigned short* __restrict__ Wk, const unsigned short* __restrict__ Wv,
    unsigned short* __restrict__ Qf, unsigned short* __restrict__ Kf,
    unsigned short* __restrict__ Vt)
{
    const int lid0 = blockIdx.x;          // 0..767
    const int xcd = lid0 & 7;
    const int jj = lid0 >> 3;             // 0..95
    const int g = xcd * 6 + (jj >> 4);    // 0..47
    const int xb = jj & 15;
    const int z = g >> 4;                 // 0..2
    const int yb = g & 15;

    const unsigned short* X = z == 0 ? Xq : (z == 1 ? Xk : Xv);
    const unsigned short* W = z == 0 ? Wq : (z == 1 ? Wk : Wv);

    __shared__ unsigned short Ab[128][72];
    __shared__ unsigned short Bb[64][72];

    const int t = threadIdx.x;
    const int w = t >> 6, lane = t & 63, qg = lane >> 4, lr = lane & 15;
    const int wr = w >> 1, wc = w & 1;
    const int mbase = yb * 128, nbase = xb * 64;

    const int arow[4] = { (t) >> 3, (t + 256) >> 3, (t + 512) >> 3, (t + 768) >> 3 };
    const int ac8 = (t & 7) << 3;
    const int brow[2] = { (t) >> 3, (t + 256) >> 3 };

    f32x4 acc[4][2] = {};
    bf16x8 pa[4], pb[2];

#pragma unroll
    for (int rr = 0; rr < 4; ++rr)
        pa[rr] = *(const bf16x8*)&X[(size_t)(mbase + arow[rr]) * DM + ac8];
#pragma unroll
    for (int rr = 0; rr < 2; ++rr)
        pb[rr] = *(const bf16x8*)&W[(size_t)(nbase + brow[rr]) * DM + ac8];

    for (int kt = 0; kt < 16; ++kt) {
#pragma unroll
        for (int rr = 0; rr < 4; ++rr)
            *(bf16x8*)&Ab[arow[rr]][ac8] = pa[rr];
#pragma unroll
        for (int rr = 0; rr < 2; ++rr)
            *(bf16x8*)&Bb[brow[rr]][ac8] = pb[rr];
        __syncthreads();

        if (kt < 15) {
            const int kb = (kt + 1) * 64;
#pragma unroll
            for (int rr = 0; rr < 4; ++rr)
                pa[rr] = *(const bf16x8*)&X[(size_t)(mbase + arow[rr]) * DM + kb + ac8];
#pragma unroll
            for (int rr = 0; rr < 2; ++rr)
                pb[rr] = *(const bf16x8*)&W[(size_t)(nbase + brow[rr]) * DM + kb + ac8];
        }

#pragma unroll
        for (int ks = 0; ks < 2; ++ks) {
            const int k0 = ks * 32 + qg * 8;
            bf16x8 a[4], bfr[2];
#pragma unroll
            for (int i = 0; i < 4; ++i)
                a[i] = *(const bf16x8*)&Ab[wr * 64 + i * 16 + lr][k0];
#pragma unroll
            for (int j = 0; j < 2; ++j)
                bfr[j] = *(const bf16x8*)&Bb[wc * 32 + j * 16 + lr][k0];
#pragma unroll
            for (int i = 0; i < 4; ++i)
#pragma unroll
                for (int j = 0; j < 2; ++j)
                    acc[i][j] = MFMA(a[i], bfr[j], acc[i][j]);
        }
        __syncthreads();
    }

    if (z < 2) {
        unsigned short* Of = z ? Kf : Qf;
        const int b = mbase >> 10, h = nbase >> 6;
        const int bh = b * NH + h;
        const int tile0 = (mbase & 1023) >> 4;
        const size_t plane = ((size_t)bh * 64 + tile0) * 1024;
        unsigned short* Lh = &Ab[0][0];   // 16 KB repack buffer

#pragma unroll
        for (int i = 0; i < 4; ++i)
#pragma unroll
            for (int j = 0; j < 2; ++j) {
                int d = wc * 32 + j * 16 + lr;
                int ks = d >> 5, qg_p = (d >> 3) & 3, e = d & 7;
                int ti = wr * 4 + i;
#pragma unroll
                for (int r = 0; r < 4; ++r) {
                    int lane_p = qg_p * 16 + qg * 4 + r;
                    Lh[((ti * 2 + ks) * 64 + lane_p) * 8 + e] = f2h(acc[i][j][r]);
                }
            }
        __syncthreads();
#pragma unroll
        for (int cch = 0; cch < 4; ++cch) {
            int f = cch * 2048 + t * 8;
            *(bf16x8*)&Of[plane + f] = *(const bf16x8*)&Lh[f];
        }
    } else {
#pragma unroll
        for (int i = 0; i < 4; ++i)
#pragma unroll
            for (int j = 0; j < 2; ++j) {
                int n = nbase + wc * 32 + j * 16 + lr;
                int h = n >> 6, d = n & 63;
                int fb = d >> 4, lr2 = d & 15;
                int m0 = mbase + wr * 64 + i * 16 + qg * 4;
                int b = m0 >> 10, l0 = m0 & 1023;
                int s = l0 >> 5, qg2 = (l0 >> 3) & 3, e0 = l0 & 7;
                int bh = b * NH + h;
                size_t idx = (((size_t)bh * 4 + fb) * 32 + s) * 512 + qg2 * 128 + lr2 * 8 + e0;
                ushort4 o;
                o.x = f2h(acc[i][j][0]); o.y = f2h(acc[i][j][1]);
                o.z = f2h(acc[i][j][2]); o.w = f2h(acc[i][j][3]);
                *(ushort4*)&Vt[idx] = o;
            }
    }
}

// ---------------------------------------------------------------------------
// Fused attention. Block = (32 Q-rows, one bh). 512 thr, 8 waves. grid 1024.
// fp16 end-to-end score/P path; T5 setprio around MFMA clusters.
// ---------------------------------------------------------------------------
#define SSTR 1048
__global__ __launch_bounds__(512, 4) void attn_kernel(
    const unsigned short* __restrict__ Qf, const unsigned short* __restrict__ Kf,
    const unsigned short* __restrict__ Vt, const unsigned short* __restrict__ Mp,
    unsigned short* __restrict__ AO)
{
    __shared__ unsigned short Sb[32 * SSTR];   // fp16 scores, then fp16 probs

    const int t = threadIdx.x;
    const int w = t >> 6, lane = t & 63, qg = lane >> 4, lr = lane & 15;
    const int lid = blockIdx.y * 32 + blockIdx.x;
    const int xcd = lid & 7;
    const int rest = lid >> 3;
    const int qt = rest & 31;
    const int bh = xcd * 4 + (rest >> 5);
    const int b = bh >> 4, h = bh & 15;
    const size_t plane = (size_t)bh << 16;

    // ---- Phase 1: transposed QK^T (fp16) ----
    f16x8 qf_[2][2];
#pragma unroll
    for (int i = 0; i < 2; ++i)
#pragma unroll
        for (int ks = 0; ks < 2; ++ks) {
            size_t qa = plane + (size_t)(qt * 2 + i) * 1024 + ks * 512 + lane * 8;
            qf_[i][ks] = *(const f16x8*)&Qf[qa];
        }

#pragma unroll
    for (int j = 0; j < 8; ++j) {
        const int kblk = w * 8 + j;
        const size_t ka = plane + (size_t)kblk * 1024 + lane * 8;
        f16x8 kf0 = *(const f16x8*)&Kf[ka];
        f16x8 kf1 = *(const f16x8*)&Kf[ka + 512];
#pragma unroll
        for (int i = 0; i < 2; ++i) {
            f32x4 acc = {};
            __builtin_amdgcn_s_setprio(1);
            acc = MFMA16(kf0, qf_[i][0], acc);
            acc = MFMA16(kf1, qf_[i][1], acc);
            __builtin_amdgcn_s_setprio(0);
            ushort4 mb = *(const ushort4*)&Mp[(((size_t)(qt * 2 + i) * 64 + kblk) * 64 + lane) * 4];
            float s0 = fmaf(acc[0], 0.0625f, h2f(mb.x));
            float s1 = fmaf(acc[1], 0.0625f, h2f(mb.y));
            float s2 = fmaf(acc[2], 0.0625f, h2f(mb.z));
            float s3 = fmaf(acc[3], 0.0625f, h2f(mb.w));
            ushort4 pk;
            pk.x = f2h(s0); pk.y = f2h(s1); pk.z = f2h(s2); pk.w = f2h(s3);
            *(ushort4*)&Sb[(i * 16 + lr) * SSTR + kblk * 16 + qg * 4] = pk;
        }
    }
    __syncthreads();

    // ---- Phase 2: entmax-1.5, packed fp16, two interleaved solves ----
    const int half_id = lane >> 5;
    const int c = lane & 31;
    const int r0 = w * 2 + half_id;
    const int r1 = 16 + r0;
    h2 x0[16], x1[16];
#pragma unroll
    for (int j = 0; j < 4; ++j) {
        uint4 u0 = *(const uint4*)&Sb[r0 * SSTR + c * 8 + 256 * j];
        uint4 u1 = *(const uint4*)&Sb[r1 * SSTR + c * 8 + 256 * j];
        const h2* p0 = (const h2*)&u0;
        const h2* p1 = (const h2*)&u1;
#pragma unroll
        for (int m = 0; m < 4; ++m) {
            x0[4 * j + m] = p0[m];
            x1[4 * j + m] = p1[m];
        }
    }

    h2 mp0 = x0[0], mp1 = x1[0];
#pragma unroll
    for (int i = 1; i < 16; ++i) {
        mp0 = h2max(mp0, x0[i]);
        mp1 = h2max(mp1, x1[i]);
    }
    float m0 = fmaxf((float)mp0[0], (float)mp0[1]);
    float m1 = fmaxf((float)mp1[0], (float)mp1[1]);
#pragma unroll
    for (int off = 1; off < 32; off <<= 1) {
        m0 = fmaxf(m0, __shfl_xor(m0, off));
        m1 = fmaxf(m1, __shfl_xor(m1, off));
    }
    {
        h2 m02 = h2splat(m0), m12 = h2splat(m1);
#pragma unroll
        for (int i = 0; i < 16; ++i) {
            x0[i] = x0[i] - m02;
            x1[i] = x1[i] - m12;
        }
    }

    const h2 zero2 = h2splat(0.0f);
    const h2 one2 = h2splat(1.0f);
    float lo0 = -1.0f, hi0 = 0.0f, lo1 = -1.0f, hi1 = 0.0f;
    for (int it = 0; it < 3; ++it) {
        float mid0 = 0.5f * (lo0 + hi0), mid1 = 0.5f * (lo1 + hi1);
        h2 mid02 = h2splat(mid0), mid12 = h2splat(mid1);
        float f0 = 0.0f, f1 = 0.0f;
#pragma unroll
        for (int i = 0; i < 16; ++i) {
            h2 a = h2max(x0[i] - mid02, zero2);
            h2 bq = h2max(x1[i] - mid12, zero2);
            f0 = dot2acc(a, a, f0);
            f1 = dot2acc(bq, bq, f1);
        }
#pragma unroll
        for (int off = 1; off < 32; off <<= 1) {
            f0 += __shfl_xor(f0, off);
            f1 += __shfl_xor(f1, off);
        }
        if (f0 >= 1.0f) lo0 = mid0; else hi0 = mid0;
        if (f1 >= 1.0f) lo1 = mid1; else hi1 = mid1;
    }
    float tau0 = lo0, tau1 = lo1;
    for (int it = 0; it < 2; ++it) {
        h2 t02 = h2splat(tau0), t12 = h2splat(tau1);
        float a1 = 0.0f, a2 = 0.0f, b1 = 0.0f, b2 = 0.0f;
#pragma unroll
        for (int i = 0; i < 16; ++i) {
            h2 a = h2max(x0[i] - t02, zero2);
            h2 bq = h2max(x1[i] - t12, zero2);
            a1 = dot2acc(a, one2, a1);
            a2 = dot2acc(a, a, a2);
            b1 = dot2acc(bq, one2, b1);
            b2 = dot2acc(bq, bq, b2);
        }
#pragma unroll
        for (int off = 1; off < 32; off <<= 1) {
            a1 += __shfl_xor(a1, off);
            a2 += __shfl_xor(a2, off);
            b1 += __shfl_xor(b1, off);
            b2 += __shfl_xor(b2, off);
        }
        tau0 += (a2 - 1.0f) / (2.0f * a1);
        tau1 += (b2 - 1.0f) / (2.0f * b1);
    }

    // ---- P = relu(x - tau)^2, packed fp16, stored fp16 in place ----
    {
        h2 t02 = h2splat(tau0), t12 = h2splat(tau1);
#pragma unroll
        for (int j = 0; j < 4; ++j) {
            uint4 u0, u1;
            h2* o0 = (h2*)&u0;
            h2* o1 = (h2*)&u1;
#pragma unroll
            for (int m = 0; m < 4; ++m) {
                h2 ra = h2max(x0[4 * j + m] - t02, zero2);
                h2 rb = h2max(x1[4 * j + m] - t12, zero2);
                o0[m] = ra * ra;
                o1[m] = rb * rb;
            }
            *(uint4*)&Sb[r0 * SSTR + c * 8 + 256 * j] = u0;
            *(uint4*)&Sb[r1 * SSTR + c * 8 + 256 * j] = u1;
        }
    }
    __syncthreads();

    // ---- Phase 3: PV from fp16 Vt, f16 MFMA ----
    const int i3 = w >> 2;
    const int fb = w & 3;
    const unsigned short* VtB = Vt + ((size_t)bh * 4 + fb) * 32 * 512 + lane * 8;
    const unsigned short* Prow = &Sb[(i3 * 16 + lr) * SSTR + qg * 8];
    f32x4 pacc = {};
    __builtin_amdgcn_s_setprio(1);
#pragma unroll
    for (int s = 0; s < 32; ++s) {
        f16x8 pa = *(const f16x8*)&Prow[s * 32];
        f16x8 vb = *(const f16x8*)&VtB[s * 512];
        pacc = MFMA16(pa, vb, pacc);
    }
    __builtin_amdgcn_s_setprio(0);
#pragma unroll
    for (int r = 0; r < 4; ++r) {
        int m = b * L + qt * 32 + i3 * 16 + qg * 4 + r;
        int d = fb * 16 + lr;
        AO[(size_t)m * DM + h * DK + d] = f2bf(pacc[r]);
    }
}

// ---------------------------------------------------------------------------
// Out projection: out = AO(bf16) @ Wo^T(bf16), fp32 out. T14 pipeline.
// BM=64, BN=64, BK=64, 4 waves. grid 512 flat, XCD remap.
// ---------------------------------------------------------------------------
__global__ __launch_bounds__(256) void out_kernel(
    const unsigned short* __restrict__ A, const unsigned short* __restrict__ W,
    float* __restrict__ O)
{
    __shared__ unsigned short Ab[64][72];
    __shared__ unsigned short Bb[64][72];

    const int lid0 = blockIdx.x;        // 0..511
    const int xcd = lid0 & 7;
    const int jj = lid0 >> 3;           // 0..63
    const int yb = xcd * 4 + (jj & 3);  // 0..31
    const int xb = jj >> 2;             // 0..15

    const int t = threadIdx.x;
    const int w = t >> 6, lane = t & 63, qg = lane >> 4, lr = lane & 15;
    const int wr = w >> 1, wc = w & 1;
    const int mbase = yb * 64, nbase = xb * 64;

    const int row0 = t >> 3, row1 = (t + 256) >> 3;
    const int c8 = (t & 7) << 3;

    f32x4 acc[2][2] = {};
    bf16x8 pa[2], pb[2];

    pa[0] = *(const bf16x8*)&A[(size_t)(mbase + row0) * DM + c8];
    pa[1] = *(const bf16x8*)&A[(size_t)(mbase + row1) * DM + c8];
    pb[0] = *(const bf16x8*)&W[(size_t)(nbase + row0) * DM + c8];
    pb[1] = *(const bf16x8*)&W[(size_t)(nbase + row1) * DM + c8];

    for (int kt = 0; kt < 16; ++kt) {
        *(bf16x8*)&Ab[row0][c8] = pa[0];
        *(bf16x8*)&Ab[row1][c8] = pa[1];
        *(bf16x8*)&Bb[row0][c8] = pb[0];
        *(bf16x8*)&Bb[row1][c8] = pb[1];
        __syncthreads();

        if (kt < 15) {
            const int kb = (kt + 1) * 64;
            pa[0] = *(const bf16x8*)&A[(size_t)(mbase + row0) * DM + kb + c8];
            pa[1] = *(const bf16x8*)&A[(size_t)(mbase + row1) * DM + kb + c8];
            pb[0] = *(const bf16x8*)&W[(size_t)(nbase + row0) * DM + kb + c8];
            pb[1] = *(const bf16x8*)&W[(size_t)(nbase + row1) * DM + kb + c8];
        }

#pragma unroll
        for (int ks = 0; ks < 2; ++ks) {
            const int k0 = ks * 32 + qg * 8;
            bf16x8 a[2], bfr[2];
#pragma unroll
            for (int i = 0; i < 2; ++i)
                a[i] = *(const bf16x8*)&Ab[wr * 32 + i * 16 + lr][k0];
#pragma unroll
            for (int j = 0; j < 2; ++j)
                bfr[j] = *(const bf16x8*)&Bb[wc * 32 + j * 16 + lr][k0];
#pragma unroll
            for (int i = 0; i < 2; ++i)
#pragma unroll
                for (int j = 0; j < 2; ++j)
                    acc[i][j] = MFMA(a[i], bfr[j], acc[i][j]);
        }
        __syncthreads();
    }

#pragma unroll
    for (int i = 0; i < 2; ++i)
#pragma unroll
        for (int j = 0; j < 2; ++j)
#pragma unroll
            for (int r = 0; r < 4; ++r) {
                int m = mbase + wr * 32 + i * 16 + qg * 4 + r;
                int n = nbase + wc * 32 + j * 16 + lr;
                O[(size_t)m * DM + n] = acc[i][j][r];
            }
}

extern "C" void kernel_launch(void* const* d_in, const int* in_sizes, int n_in,
                              void* d_out, int out_size, void* d_ws, size_t ws_size,
                              hipStream_t stream)
{
    const float* q  = (const float*)d_in[0];
    const float* k  = (const float*)d_in[1];
    const float* v  = (const float*)d_in[2];
    const int* mask = (const int*)d_in[3];
    const float* wq = (const float*)d_in[4];
    const float* wk = (const float*)d_in[5];
    const float* wv = (const float*)d_in[6];
    const float* wo = (const float*)d_in[7];

    char* wsb = (char*)d_ws;
    const size_t MB = (size_t)1 << 20;
    unsigned short* Qf  = (unsigned short*)(wsb + 0 * MB);
    unsigned short* Kf  = (unsigned short*)(wsb + 4 * MB);
    unsigned short* Vt  = (unsigned short*)(wsb + 8 * MB);
    unsigned short* AO  = (unsigned short*)(wsb + 12 * MB);
    unsigned short* Xqb = (unsigned short*)(wsb + 16 * MB);
    unsigned short* Xkb = (unsigned short*)(wsb + 20 * MB);
    unsigned short* Xvb = (unsigned short*)(wsb + 24 * MB);
    unsigned short* Wqb = (unsigned short*)(wsb + 28 * MB);
    unsigned short* Wkb = (unsigned short*)(wsb + 30 * MB);
    unsigned short* Wvb = (unsigned short*)(wsb + 32 * MB);
    unsigned short* Wob = (unsigned short*)(wsb + 34 * MB);
    unsigned short* Mp  = (unsigned short*)(wsb + 36 * MB);

    prep_kernel<<<dim3(1024), 256, 0, stream>>>(q, k, v, wq, wk, wv, wo, mask,
                                                Xqb, Xkb, Xvb, Wqb, Wkb, Wvb, Wob, Mp);
    proj_kernel<<<dim3(768), 256, 0, stream>>>(Xqb, Xkb, Xvb, Wqb, Wkb, Wvb,
                                               Qf, Kf, Vt);
    attn_kernel<<<dim3(32, 32), 512, 0, stream>>>(Qf, Kf, Vt, Mp, AO);
    out_kernel<<<dim3(512), 256, 0, stream>>>(AO, Wob, (float*)d_out);
}

// Round 19
// 80.482 us; speedup vs baseline: 1.0407x; 1.0407x over previous
//
#include <hip/hip_runtime.h>

#define L 1024
#define DM 1024
#define NH 16
#define DK 64

typedef __attribute__((ext_vector_type(8))) short bf16x8;
typedef __attribute__((ext_vector_type(4))) float f32x4;
typedef _Float16 h2 __attribute__((ext_vector_type(2)));
typedef _Float16 f16x8 __attribute__((ext_vector_type(8)));

#define MFMA(a, b, c) __builtin_amdgcn_mfma_f32_16x16x32_bf16(a, b, c, 0, 0, 0)
#define MFMA16(a, b, c) __builtin_amdgcn_mfma_f32_16x16x32_f16(a, b, c, 0, 0, 0)

__device__ inline unsigned short f2bf(float f) {
    unsigned int u = __builtin_bit_cast(unsigned int, f);
    u += 0x7FFFu + ((u >> 16) & 1u);
    return (unsigned short)(u >> 16);
}
__device__ inline unsigned short f2h(float f) {
    return __builtin_bit_cast(unsigned short, (_Float16)f);
}
__device__ inline float h2f(unsigned short u) {
    return (float)__builtin_bit_cast(_Float16, u);
}

__device__ inline h2 h2splat(float v) {
    h2 r; r[0] = (_Float16)v; r[1] = (_Float16)v; return r;
}
__device__ inline h2 h2max(h2 a, h2 b) {
#if defined(__has_builtin)
#if __has_builtin(__builtin_elementwise_max)
    return __builtin_elementwise_max(a, b);
#else
    h2 r; r[0] = a[0] > b[0] ? a[0] : b[0]; r[1] = a[1] > b[1] ? a[1] : b[1]; return r;
#endif
#else
    h2 r; r[0] = a[0] > b[0] ? a[0] : b[0]; r[1] = a[1] > b[1] ? a[1] : b[1]; return r;
#endif
}

// f32-accumulating fp16 pair dot
__device__ inline float dot2acc(h2 a, h2 b, float c) {
#if defined(__has_builtin)
#if __has_builtin(__builtin_amdgcn_fdot2)
    return __builtin_amdgcn_fdot2(a, b, c, false);
#else
    return c + (float)a[0] * (float)b[0] + (float)a[1] * (float)b[1];
#endif
#else
    return c + (float)a[0] * (float)b[0] + (float)a[1] * (float)b[1];
#endif
}

// ---------------------------------------------------------------------------
// Prep: fp32 -> bf16 conversion of GEMM inputs + mask -> fp16 bias fragments.
// (bf16 pre-conversion is load-bearing: keeps proj's per-XCD L2 set 3.5 MB.)
// ---------------------------------------------------------------------------
__global__ __launch_bounds__(256) void prep_kernel(
    const float* __restrict__ q, const float* __restrict__ k, const float* __restrict__ v,
    const float* __restrict__ wq, const float* __restrict__ wk,
    const float* __restrict__ wv, const float* __restrict__ wo,
    const int* __restrict__ mask,
    unsigned short* __restrict__ Xq, unsigned short* __restrict__ Xk,
    unsigned short* __restrict__ Xv, unsigned short* __restrict__ Wq,
    unsigned short* __restrict__ Wk, unsigned short* __restrict__ Wv,
    unsigned short* __restrict__ Wo, unsigned short* __restrict__ Mp)
{
    const int id = blockIdx.x * 256 + threadIdx.x;     // 0 .. 262143
    {   // mask packing: Mp[qtile][kblk][lane][4]
        int lane = id & 63;
        int kblk = (id >> 6) & 63;
        int qtile = id >> 12;
        int qabs = qtile * 16 + (lane & 15);
        int kcol = kblk * 16 + (lane >> 4) * 4;
        int4 m = *(const int4*)&mask[(size_t)qabs * L + kcol];
        unsigned short neg = f2h(-60000.0f);
        ushort4 o;
        o.x = (m.x == 0) ? neg : (unsigned short)0;
        o.y = (m.y == 0) ? neg : (unsigned short)0;
        o.z = (m.z == 0) ? neg : (unsigned short)0;
        o.w = (m.w == 0) ? neg : (unsigned short)0;
        *(ushort4*)&Mp[(size_t)id * 4] = o;
    }

    const size_t M2 = (size_t)1 << 21, M1 = (size_t)1 << 20;
    const size_t nchunks = (3 * M2 + 4 * M1) / 8;
    const size_t stride = (size_t)gridDim.x * blockDim.x;
    for (size_t c = (size_t)id; c < nchunks; c += stride) {
        size_t e = c * 8;
        const float* src;
        unsigned short* dst;
        size_t off;
        if (e < 3 * M2) {
            size_t r = e / M2;
            off = e - r * M2;
            src = r == 0 ? q : (r == 1 ? k : v);
            dst = r == 0 ? Xq : (r == 1 ? Xk : Xv);
        } else {
            size_t e2 = e - 3 * M2;
            size_t r = e2 / M1;
            off = e2 - r * M1;
            src = r == 0 ? wq : (r == 1 ? wk : (r == 2 ? wv : wo));
            dst = r == 0 ? Wq : (r == 1 ? Wk : (r == 2 ? Wv : Wo));
        }
        float4 a = *(const float4*)&src[off];
        float4 b = *(const float4*)&src[off + 4];
        ushort4 o0, o1;
        o0.x = f2bf(a.x); o0.y = f2bf(a.y); o0.z = f2bf(a.z); o0.w = f2bf(a.w);
        o1.x = f2bf(b.x); o1.y = f2bf(b.y); o1.z = f2bf(b.z); o1.w = f2bf(b.w);
        *(ushort4*)&dst[off] = o0;
        *(ushort4*)&dst[off + 4] = o1;
    }
}

// ---------------------------------------------------------------------------
// Projections: Y = X @ W^T from pre-converted bf16. T14 pipeline (r16 win).
//  z=0/1: Q/K fp16 fragment-packed [bh][tile(64)][ks(2)][lane(64)][8]
//  z=2:   V fp16 [bh][fb(4)][s(32)][lane(64)][8]
// BM=128, BN=64, BK=64, 256 thr / 4 waves. grid 768 flat, XCD remap.
// ---------------------------------------------------------------------------
__global__ __launch_bounds__(256) void proj_kernel(
    const unsigned short* __restrict__ Xq, const unsigned short* __restrict__ Xk,
    const unsigned short* __restrict__ Xv, const unsigned short* __restrict__ Wq,
    const unsigned short* __restrict__ Wk, const unsigned short* __restrict__ Wv,
    unsigned short* __restrict__ Qf, unsigned short* __restrict__ Kf,
    unsigned short* __restrict__ Vt)
{
    const int lid0 = blockIdx.x;          // 0..767
    const int xcd = lid0 & 7;
    const int jj = lid0 >> 3;             // 0..95
    const int g = xcd * 6 + (jj >> 4);    // 0..47
    const int xb = jj & 15;
    const int z = g >> 4;                 // 0..2
    const int yb = g & 15;

    const unsigned short* X = z == 0 ? Xq : (z == 1 ? Xk : Xv);
    const unsigned short* W = z == 0 ? Wq : (z == 1 ? Wk : Wv);

    __shared__ unsigned short Ab[128][72];
    __shared__ unsigned short Bb[64][72];

    const int t = threadIdx.x;
    const int w = t >> 6, lane = t & 63, qg = lane >> 4, lr = lane & 15;
    const int wr = w >> 1, wc = w & 1;
    const int mbase = yb * 128, nbase = xb * 64;

    const int arow[4] = { (t) >> 3, (t + 256) >> 3, (t + 512) >> 3, (t + 768) >> 3 };
    const int ac8 = (t & 7) << 3;
    const int brow[2] = { (t) >> 3, (t + 256) >> 3 };

    f32x4 acc[4][2] = {};
    bf16x8 pa[4], pb[2];

#pragma unroll
    for (int rr = 0; rr < 4; ++rr)
        pa[rr] = *(const bf16x8*)&X[(size_t)(mbase + arow[rr]) * DM + ac8];
#pragma unroll
    for (int rr = 0; rr < 2; ++rr)
        pb[rr] = *(const bf16x8*)&W[(size_t)(nbase + brow[rr]) * DM + ac8];

    for (int kt = 0; kt < 16; ++kt) {
#pragma unroll
        for (int rr = 0; rr < 4; ++rr)
            *(bf16x8*)&Ab[arow[rr]][ac8] = pa[rr];
#pragma unroll
        for (int rr = 0; rr < 2; ++rr)
            *(bf16x8*)&Bb[brow[rr]][ac8] = pb[rr];
        __syncthreads();

        if (kt < 15) {
            const int kb = (kt + 1) * 64;
#pragma unroll
            for (int rr = 0; rr < 4; ++rr)
                pa[rr] = *(const bf16x8*)&X[(size_t)(mbase + arow[rr]) * DM + kb + ac8];
#pragma unroll
            for (int rr = 0; rr < 2; ++rr)
                pb[rr] = *(const bf16x8*)&W[(size_t)(nbase + brow[rr]) * DM + kb + ac8];
        }

#pragma unroll
        for (int ks = 0; ks < 2; ++ks) {
            const int k0 = ks * 32 + qg * 8;
            bf16x8 a[4], bfr[2];
#pragma unroll
            for (int i = 0; i < 4; ++i)
                a[i] = *(const bf16x8*)&Ab[wr * 64 + i * 16 + lr][k0];
#pragma unroll
            for (int j = 0; j < 2; ++j)
                bfr[j] = *(const bf16x8*)&Bb[wc * 32 + j * 16 + lr][k0];
#pragma unroll
            for (int i = 0; i < 4; ++i)
#pragma unroll
                for (int j = 0; j < 2; ++j)
                    acc[i][j] = MFMA(a[i], bfr[j], acc[i][j]);
        }
        __syncthreads();
    }

    if (z < 2) {
        unsigned short* Of = z ? Kf : Qf;
        const int b = mbase >> 10, h = nbase >> 6;
        const int bh = b * NH + h;
        const int tile0 = (mbase & 1023) >> 4;
        const size_t plane = ((size_t)bh * 64 + tile0) * 1024;
        unsigned short* Lh = &Ab[0][0];   // 16 KB repack buffer

#pragma unroll
        for (int i = 0; i < 4; ++i)
#pragma unroll
            for (int j = 0; j < 2; ++j) {
                int d = wc * 32 + j * 16 + lr;
                int ks = d >> 5, qg_p = (d >> 3) & 3, e = d & 7;
                int ti = wr * 4 + i;
#pragma unroll
                for (int r = 0; r < 4; ++r) {
                    int lane_p = qg_p * 16 + qg * 4 + r;
                    Lh[((ti * 2 + ks) * 64 + lane_p) * 8 + e] = f2h(acc[i][j][r]);
                }
            }
        __syncthreads();
#pragma unroll
        for (int cch = 0; cch < 4; ++cch) {
            int f = cch * 2048 + t * 8;
            *(bf16x8*)&Of[plane + f] = *(const bf16x8*)&Lh[f];
        }
    } else {
#pragma unroll
        for (int i = 0; i < 4; ++i)
#pragma unroll
            for (int j = 0; j < 2; ++j) {
                int n = nbase + wc * 32 + j * 16 + lr;
                int h = n >> 6, d = n & 63;
                int fb = d >> 4, lr2 = d & 15;
                int m0 = mbase + wr * 64 + i * 16 + qg * 4;
                int b = m0 >> 10, l0 = m0 & 1023;
                int s = l0 >> 5, qg2 = (l0 >> 3) & 3, e0 = l0 & 7;
                int bh = b * NH + h;
                size_t idx = (((size_t)bh * 4 + fb) * 32 + s) * 512 + qg2 * 128 + lr2 * 8 + e0;
                ushort4 o;
                o.x = f2h(acc[i][j][0]); o.y = f2h(acc[i][j][1]);
                o.z = f2h(acc[i][j][2]); o.w = f2h(acc[i][j][3]);
                *(ushort4*)&Vt[idx] = o;
            }
    }
}

// ---------------------------------------------------------------------------
// Fused attention. Block = (32 Q-rows, one bh). 512 thr, 8 waves. grid 1024.
// fp16 QK^T; entmax packed fp16 end-to-end: P stays fp16 in LDS (packed
// v_pk_mul squares), PV via f16 MFMA on fp16 Vt. XCD-locality remap.
// ---------------------------------------------------------------------------
#define SSTR 1048
__global__ __launch_bounds__(512, 4) void attn_kernel(
    const unsigned short* __restrict__ Qf, const unsigned short* __restrict__ Kf,
    const unsigned short* __restrict__ Vt, const unsigned short* __restrict__ Mp,
    unsigned short* __restrict__ AO)
{
    __shared__ unsigned short Sb[32 * SSTR];   // fp16 scores, then fp16 probs

    const int t = threadIdx.x;
    const int w = t >> 6, lane = t & 63, qg = lane >> 4, lr = lane & 15;
    const int lid = blockIdx.y * 32 + blockIdx.x;
    const int xcd = lid & 7;
    const int rest = lid >> 3;
    const int qt = rest & 31;
    const int bh = xcd * 4 + (rest >> 5);
    const int b = bh >> 4, h = bh & 15;
    const size_t plane = (size_t)bh << 16;

    // ---- Phase 1: transposed QK^T (fp16) ----
    f16x8 qf_[2][2];
#pragma unroll
    for (int i = 0; i < 2; ++i)
#pragma unroll
        for (int ks = 0; ks < 2; ++ks) {
            size_t qa = plane + (size_t)(qt * 2 + i) * 1024 + ks * 512 + lane * 8;
            qf_[i][ks] = *(const f16x8*)&Qf[qa];
        }

#pragma unroll
    for (int j = 0; j < 8; ++j) {
        const int kblk = w * 8 + j;
        const size_t ka = plane + (size_t)kblk * 1024 + lane * 8;
        f16x8 kf0 = *(const f16x8*)&Kf[ka];
        f16x8 kf1 = *(const f16x8*)&Kf[ka + 512];
#pragma unroll
        for (int i = 0; i < 2; ++i) {
            f32x4 acc = {};
            acc = MFMA16(kf0, qf_[i][0], acc);
            acc = MFMA16(kf1, qf_[i][1], acc);
            ushort4 mb = *(const ushort4*)&Mp[(((size_t)(qt * 2 + i) * 64 + kblk) * 64 + lane) * 4];
            float s0 = fmaf(acc[0], 0.0625f, h2f(mb.x));
            float s1 = fmaf(acc[1], 0.0625f, h2f(mb.y));
            float s2 = fmaf(acc[2], 0.0625f, h2f(mb.z));
            float s3 = fmaf(acc[3], 0.0625f, h2f(mb.w));
            ushort4 pk;
            pk.x = f2h(s0); pk.y = f2h(s1); pk.z = f2h(s2); pk.w = f2h(s3);
            *(ushort4*)&Sb[(i * 16 + lr) * SSTR + kblk * 16 + qg * 4] = pk;
        }
    }
    __syncthreads();

    // ---- Phase 2: entmax-1.5, packed fp16, two interleaved solves ----
    const int half_id = lane >> 5;
    const int c = lane & 31;
    const int r0 = w * 2 + half_id;
    const int r1 = 16 + r0;
    h2 x0[16], x1[16];
#pragma unroll
    for (int j = 0; j < 4; ++j) {
        uint4 u0 = *(const uint4*)&Sb[r0 * SSTR + c * 8 + 256 * j];
        uint4 u1 = *(const uint4*)&Sb[r1 * SSTR + c * 8 + 256 * j];
        const h2* p0 = (const h2*)&u0;
        const h2* p1 = (const h2*)&u1;
#pragma unroll
        for (int m = 0; m < 4; ++m) {
            x0[4 * j + m] = p0[m];
            x1[4 * j + m] = p1[m];
        }
    }

    h2 mp0 = x0[0], mp1 = x1[0];
#pragma unroll
    for (int i = 1; i < 16; ++i) {
        mp0 = h2max(mp0, x0[i]);
        mp1 = h2max(mp1, x1[i]);
    }
    float m0 = fmaxf((float)mp0[0], (float)mp0[1]);
    float m1 = fmaxf((float)mp1[0], (float)mp1[1]);
#pragma unroll
    for (int off = 1; off < 32; off <<= 1) {
        m0 = fmaxf(m0, __shfl_xor(m0, off));
        m1 = fmaxf(m1, __shfl_xor(m1, off));
    }
    {
        h2 m02 = h2splat(m0), m12 = h2splat(m1);
#pragma unroll
        for (int i = 0; i < 16; ++i) {
            x0[i] = x0[i] - m02;
            x1[i] = x1[i] - m12;
        }
    }

    const h2 zero2 = h2splat(0.0f);
    const h2 one2 = h2splat(1.0f);
    float lo0 = -1.0f, hi0 = 0.0f, lo1 = -1.0f, hi1 = 0.0f;
    for (int it = 0; it < 3; ++it) {
        float mid0 = 0.5f * (lo0 + hi0), mid1 = 0.5f * (lo1 + hi1);
        h2 mid02 = h2splat(mid0), mid12 = h2splat(mid1);
        float f0 = 0.0f, f1 = 0.0f;
#pragma unroll
        for (int i = 0; i < 16; ++i) {
            h2 a = h2max(x0[i] - mid02, zero2);
            h2 bq = h2max(x1[i] - mid12, zero2);
            f0 = dot2acc(a, a, f0);
            f1 = dot2acc(bq, bq, f1);
        }
#pragma unroll
        for (int off = 1; off < 32; off <<= 1) {
            f0 += __shfl_xor(f0, off);
            f1 += __shfl_xor(f1, off);
        }
        if (f0 >= 1.0f) lo0 = mid0; else hi0 = mid0;
        if (f1 >= 1.0f) lo1 = mid1; else hi1 = mid1;
    }
    float tau0 = lo0, tau1 = lo1;
    for (int it = 0; it < 2; ++it) {
        h2 t02 = h2splat(tau0), t12 = h2splat(tau1);
        float a1 = 0.0f, a2 = 0.0f, b1 = 0.0f, b2 = 0.0f;
#pragma unroll
        for (int i = 0; i < 16; ++i) {
            h2 a = h2max(x0[i] - t02, zero2);
            h2 bq = h2max(x1[i] - t12, zero2);
            a1 = dot2acc(a, one2, a1);
            a2 = dot2acc(a, a, a2);
            b1 = dot2acc(bq, one2, b1);
            b2 = dot2acc(bq, bq, b2);
        }
#pragma unroll
        for (int off = 1; off < 32; off <<= 1) {
            a1 += __shfl_xor(a1, off);
            a2 += __shfl_xor(a2, off);
            b1 += __shfl_xor(b1, off);
            b2 += __shfl_xor(b2, off);
        }
        tau0 += (a2 - 1.0f) / (2.0f * a1);
        tau1 += (b2 - 1.0f) / (2.0f * b1);
    }

    // ---- P = relu(x - tau)^2, packed fp16, stored fp16 in place ----
    {
        h2 t02 = h2splat(tau0), t12 = h2splat(tau1);
#pragma unroll
        for (int j = 0; j < 4; ++j) {
            uint4 u0, u1;
            h2* o0 = (h2*)&u0;
            h2* o1 = (h2*)&u1;
#pragma unroll
            for (int m = 0; m < 4; ++m) {
                h2 ra = h2max(x0[4 * j + m] - t02, zero2);
                h2 rb = h2max(x1[4 * j + m] - t12, zero2);
                o0[m] = ra * ra;
                o1[m] = rb * rb;
            }
            *(uint4*)&Sb[r0 * SSTR + c * 8 + 256 * j] = u0;
            *(uint4*)&Sb[r1 * SSTR + c * 8 + 256 * j] = u1;
        }
    }
    __syncthreads();

    // ---- Phase 3: PV from fp16 Vt, f16 MFMA ----
    const int i3 = w >> 2;
    const int fb = w & 3;
    const unsigned short* VtB = Vt + ((size_t)bh * 4 + fb) * 32 * 512 + lane * 8;
    const unsigned short* Prow = &Sb[(i3 * 16 + lr) * SSTR + qg * 8];
    f32x4 pacc = {};
#pragma unroll
    for (int s = 0; s < 32; ++s) {
        f16x8 pa = *(const f16x8*)&Prow[s * 32];
        f16x8 vb = *(const f16x8*)&VtB[s * 512];
        pacc = MFMA16(pa, vb, pacc);
    }
#pragma unroll
    for (int r = 0; r < 4; ++r) {
        int m = b * L + qt * 32 + i3 * 16 + qg * 4 + r;
        int d = fb * 16 + lr;
        AO[(size_t)m * DM + h * DK + d] = f2bf(pacc[r]);
    }
}

// ---------------------------------------------------------------------------
// Out projection: out = AO(bf16) @ Wo^T(bf16), fp32 out. T14 pipeline.
// BM=64, BN=64, BK=64, 4 waves. grid 512 flat, XCD remap.
// ---------------------------------------------------------------------------
__global__ __launch_bounds__(256) void out_kernel(
    const unsigned short* __restrict__ A, const unsigned short* __restrict__ W,
    float* __restrict__ O)
{
    __shared__ unsigned short Ab[64][72];
    __shared__ unsigned short Bb[64][72];

    const int lid0 = blockIdx.x;        // 0..511
    const int xcd = lid0 & 7;
    const int jj = lid0 >> 3;           // 0..63
    const int yb = xcd * 4 + (jj & 3);  // 0..31
    const int xb = jj >> 2;             // 0..15

    const int t = threadIdx.x;
    const int w = t >> 6, lane = t & 63, qg = lane >> 4, lr = lane & 15;
    const int wr = w >> 1, wc = w & 1;
    const int mbase = yb * 64, nbase = xb * 64;

    const int row0 = t >> 3, row1 = (t + 256) >> 3;
    const int c8 = (t & 7) << 3;

    f32x4 acc[2][2] = {};
    bf16x8 pa[2], pb[2];

    pa[0] = *(const bf16x8*)&A[(size_t)(mbase + row0) * DM + c8];
    pa[1] = *(const bf16x8*)&A[(size_t)(mbase + row1) * DM + c8];
    pb[0] = *(const bf16x8*)&W[(size_t)(nbase + row0) * DM + c8];
    pb[1] = *(const bf16x8*)&W[(size_t)(nbase + row1) * DM + c8];

    for (int kt = 0; kt < 16; ++kt) {
        *(bf16x8*)&Ab[row0][c8] = pa[0];
        *(bf16x8*)&Ab[row1][c8] = pa[1];
        *(bf16x8*)&Bb[row0][c8] = pb[0];
        *(bf16x8*)&Bb[row1][c8] = pb[1];
        __syncthreads();

        if (kt < 15) {
            const int kb = (kt + 1) * 64;
            pa[0] = *(const bf16x8*)&A[(size_t)(mbase + row0) * DM + kb + c8];
            pa[1] = *(const bf16x8*)&A[(size_t)(mbase + row1) * DM + kb + c8];
            pb[0] = *(const bf16x8*)&W[(size_t)(nbase + row0) * DM + kb + c8];
            pb[1] = *(const bf16x8*)&W[(size_t)(nbase + row1) * DM + kb + c8];
        }

#pragma unroll
        for (int ks = 0; ks < 2; ++ks) {
            const int k0 = ks * 32 + qg * 8;
            bf16x8 a[2], bfr[2];
#pragma unroll
            for (int i = 0; i < 2; ++i)
                a[i] = *(const bf16x8*)&Ab[wr * 32 + i * 16 + lr][k0];
#pragma unroll
            for (int j = 0; j < 2; ++j)
                bfr[j] = *(const bf16x8*)&Bb[wc * 32 + j * 16 + lr][k0];
#pragma unroll
            for (int i = 0; i < 2; ++i)
#pragma unroll
                for (int j = 0; j < 2; ++j)
                    acc[i][j] = MFMA(a[i], bfr[j], acc[i][j]);
        }
        __syncthreads();
    }

#pragma unroll
    for (int i = 0; i < 2; ++i)
#pragma unroll
        for (int j = 0; j < 2; ++j)
#pragma unroll
            for (int r = 0; r < 4; ++r) {
                int m = mbase + wr * 32 + i * 16 + qg * 4 + r;
                int n = nbase + wc * 32 + j * 16 + lr;
                O[(size_t)m * DM + n] = acc[i][j][r];
            }
}

extern "C" void kernel_launch(void* const* d_in, const int* in_sizes, int n_in,
                              void* d_out, int out_size, void* d_ws, size_t ws_size,
                              hipStream_t stream)
{
    const float* q  = (const float*)d_in[0];
    const float* k  = (const float*)d_in[1];
    const float* v  = (const float*)d_in[2];
    const int* mask = (const int*)d_in[3];
    const float* wq = (const float*)d_in[4];
    const float* wk = (const float*)d_in[5];
    const float* wv = (const float*)d_in[6];
    const float* wo = (const float*)d_in[7];

    char* wsb = (char*)d_ws;
    const size_t MB = (size_t)1 << 20;
    unsigned short* Qf  = (unsigned short*)(wsb + 0 * MB);
    unsigned short* Kf  = (unsigned short*)(wsb + 4 * MB);
    unsigned short* Vt  = (unsigned short*)(wsb + 8 * MB);
    unsigned short* AO  = (unsigned short*)(wsb + 12 * MB);
    unsigned short* Xqb = (unsigned short*)(wsb + 16 * MB);
    unsigned short* Xkb = (unsigned short*)(wsb + 20 * MB);
    unsigned short* Xvb = (unsigned short*)(wsb + 24 * MB);
    unsigned short* Wqb = (unsigned short*)(wsb + 28 * MB);
    unsigned short* Wkb = (unsigned short*)(wsb + 30 * MB);
    unsigned short* Wvb = (unsigned short*)(wsb + 32 * MB);
    unsigned short* Wob = (unsigned short*)(wsb + 34 * MB);
    unsigned short* Mp  = (unsigned short*)(wsb + 36 * MB);

    prep_kernel<<<dim3(1024), 256, 0, stream>>>(q, k, v, wq, wk, wv, wo, mask,
                                                Xqb, Xkb, Xvb, Wqb, Wkb, Wvb, Wob, Mp);
    proj_kernel<<<dim3(768), 256, 0, stream>>>(Xqb, Xkb, Xvb, Wqb, Wkb, Wvb,
                                               Qf, Kf, Vt);
    attn_kernel<<<dim3(32, 32), 512, 0, stream>>>(Qf, Kf, Vt, Mp, AO);
    out_kernel<<<dim3(512), 256, 0, stream>>>(AO, Wob, (float*)d_out);
}